// Round 3
// baseline (149.056 us; speedup 1.0000x reference)
//
#include <hip/hip_runtime.h>
#include <hip/hip_bf16.h>

// Problem constants
#define B_    64
#define C_    64
#define N_    22
#define T_    1024
#define O_    64
#define KTOT  1408      // C_*N_
#define KSTEPS 44       // KTOT/32

typedef __bf16 bf16x8 __attribute__((ext_vector_type(8)));
typedef float  f32x4  __attribute__((ext_vector_type(4)));

typedef __attribute__((address_space(1))) float f32_g;
typedef __attribute__((address_space(3))) float f32_l;

// ---------------------------------------------------------------------------
// prep1: compute C1 = s, C2 = 2 s^2 - I  (22x22 each) and const[o]
// ---------------------------------------------------------------------------
__global__ void prep1(const float* __restrict__ adjp,
                      const float* __restrict__ aggw,
                      const float* __restrict__ chebb,
                      const float* __restrict__ aggb,
                      float* __restrict__ Cbuf,    // [2][484]
                      float* __restrict__ constv)  // [64]
{
    __shared__ float adj[484];
    __shared__ float s[484];
    __shared__ float dis[22];
    int tid = threadIdx.x;

    if (tid < 484) {
        int i = tid / 22, j = tid % 22;
        float a = 0.5f * (1.f / (1.f + expf(-adjp[i * 22 + j])) +
                          1.f / (1.f + expf(-adjp[j * 22 + i])));
        if (i == j) a = 0.f;
        adj[tid] = a;
    }
    __syncthreads();
    if (tid < 22) {
        float d = 0.f;
        for (int n = 0; n < 22; ++n) d += adj[tid * 22 + n];
        dis[tid] = rsqrtf(d);
    }
    __syncthreads();
    if (tid < 484) {
        int i = tid / 22, j = tid % 22;
        float sv = -dis[i] * adj[tid] * dis[j];
        s[tid] = sv;
        Cbuf[tid] = sv;                 // C1
    }
    __syncthreads();
    if (tid < 484) {
        int i = tid / 22, j = tid % 22;
        float acc = 0.f;
        for (int n = 0; n < 22; ++n) acc += s[i * 22 + n] * s[n * 22 + j];
        Cbuf[484 + tid] = 2.f * acc - (i == j ? 1.f : 0.f);   // C2
    }
    if (tid < 64) {
        float cc = aggb[tid];
        const float* wsl = aggw + tid * (C_ * N_);
        for (int e = 0; e < C_ * N_; ++e) cc += wsl[e] * chebb[e / N_];
        constv[tid] = cc;
    }
}

// ---------------------------------------------------------------------------
// prep2: F[qi][o][c'][v] = sum_n aggw[o,c',n] * C_{qi+1}[n,v]   qi in {0,1}
// ---------------------------------------------------------------------------
__global__ void prep2(const float* __restrict__ aggw,
                      const float* __restrict__ Cbuf,
                      float* __restrict__ F)        // [2][64][1408]
{
    int qi = blockIdx.x >> 6;
    int o  = blockIdx.x & 63;
    __shared__ float Cs[484];
    __shared__ float Ws[C_ * N_];
    for (int e = threadIdx.x; e < 484; e += 256) Cs[e] = Cbuf[qi * 484 + e];
    for (int e = threadIdx.x; e < C_ * N_; e += 256) Ws[e] = aggw[o * (C_ * N_) + e];
    __syncthreads();
    for (int e = threadIdx.x; e < C_ * N_; e += 256) {
        int cp = e / N_, v = e % N_;
        float acc = 0.f;
#pragma unroll
        for (int n = 0; n < N_; ++n) acc += Ws[cp * N_ + n] * Cs[n * N_ + v];
        F[(qi * 64 + o) * (C_ * N_) + e] = acc;
    }
}

// ---------------------------------------------------------------------------
// prep3: fold into M[o,k], k=c*22+v, stored bf16 in A-fragment-major layout:
//   Mfrag[((ks*4+fo)*64 + lane)*8 + j] = M[o = fo*16 + (lane&15),
//                                          k = ks*32 + (lane>>4)*8 + j]
// ---------------------------------------------------------------------------
__global__ void prep3(const float* __restrict__ chebw,  // [3][64][64]
                      const float* __restrict__ aggw,   // [64][64][22]
                      const float* __restrict__ F,      // [2][64][1408]
                      __bf16* __restrict__ Mfrag)       // [176*512]
{
    int f  = blockIdx.x;       // 0..175
    int ks = f >> 2, fo = f & 3;
    for (int e = threadIdx.x; e < 512; e += 256) {
        int l = e >> 3, j = e & 7;
        int o = fo * 16 + (l & 15);
        int k = ks * 32 + ((l >> 4) << 3) + j;
        int c = k / N_, v = k - c * N_;
        const float* w0 = chebw + c * 64;
        const float* w1 = w0 + 4096;
        const float* w2 = w0 + 8192;
        const float* g0 = aggw + o * (C_ * N_) + v;          // q=0: C0=I -> aggw
        const float* g1 = F + o * (C_ * N_) + v;             // q=1
        const float* g2 = F + (64 + o) * (C_ * N_) + v;      // q=2
        float a0 = 0.f, a1 = 0.f, a2 = 0.f;
        for (int cp = 0; cp < 64; ++cp) {
            a0 += w0[cp] * g0[cp * N_];
            a1 += w1[cp] * g1[cp * N_];
            a2 += w2[cp] * g2[cp * N_];
        }
        Mfrag[f * 512 + e] = (__bf16)(a0 + a1 + a2);
    }
}

// ---------------------------------------------------------------------------
// main GEMM: per block (b, t-tile of 64): Y_b[64, t0:t0+64] = M @ X_b
// Deep pipeline: 4 LDS buffers, stage distance 3 (~900+ cyc HBM latency
// coverage), A-reg double buffer distance 2, counted vmcnt(6) steady state
// (never 0 in main loop). XCD-aware block swizzle (1024 % 8 == 0, bijective).
// ---------------------------------------------------------------------------
#define WAITV(N) asm volatile("s_waitcnt vmcnt(" #N ")" ::: "memory")
#define BARR do { __builtin_amdgcn_s_barrier(); __builtin_amdgcn_sched_barrier(0); } while (0)

__global__ __launch_bounds__(256, 4) void gemm_main(
    const float* __restrict__ x,
    const __bf16* __restrict__ Mfrag,
    const float* __restrict__ constv,
    float* __restrict__ y)
{
    __shared__ float lds[4 * 2048];   // 4 x [32 k][64 t] fp32 = 32 KB

    // XCD swizzle: XCD k executes logical tiles [k*128, (k+1)*128) ->
    // each b-group of 16 tiles lives on a single XCD.
    const int bid  = ((blockIdx.x & 7) << 7) | (blockIdx.x >> 3);
    const int b    = bid >> 4;
    const int tt   = bid & 15;
    const int wave = threadIdx.x >> 6;
    const int lane = threadIdx.x & 63;
    const int tcol = lane & 15;
    const int kg   = lane >> 4;

    // ---- staging: wave w covers rows w*4..w*4+3 and 16+w*4..16+w*4+3 ----
    // LDS dest linear (gload_lds requirement); swizzle applied on SOURCE:
    // LDS[k][chunk c] holds global t-chunk  g = c ^ (((k>>3)&3)<<1)
    const int rA = wave * 4 + kg;
    const int rB = rA + 16;
    const int gA = tcol ^ (((rA >> 3) & 3) << 1);
    const int gB = tcol ^ (((rB >> 3) & 3) << 1);
    const float* srcA = x + (size_t)b * (KTOT * T_) + (size_t)rA * T_ + tt * 64 + gA * 4;
    const float* srcB = x + (size_t)b * (KTOT * T_) + (size_t)rB * T_ + tt * 64 + gB * 4;
    const int dstA = (wave * 4) * 64;        // float offset, wave-uniform
    const int dstB = (16 + wave * 4) * 64;

    // ---- fragment read addressing (inverse swizzle) ----
    const int c_rd   = (wave * 4 + (tcol >> 2)) ^ (kg << 1);
    const int rd_off = kg * 512 + c_rd * 4 + (tcol & 3);   // + j*64 per j

    const __bf16* mf = Mfrag + (size_t)lane * 8;

    f32x4 acc[4];
#pragma unroll
    for (int fo = 0; fo < 4; ++fo) acc[fo] = (f32x4){0.f, 0.f, 0.f, 0.f};

    auto STAGE = [&](int ks, float* buf) {
        const float* s1 = srcA + (size_t)ks * (32 * T_);
        const float* s2 = srcB + (size_t)ks * (32 * T_);
        __builtin_amdgcn_global_load_lds((const f32_g*)s1, (f32_l*)(buf + dstA), 16, 0, 0);
        __builtin_amdgcn_global_load_lds((const f32_g*)s2, (f32_l*)(buf + dstB), 16, 0, 0);
    };
    auto PREFA = [&](bf16x8* dst, int ks) {
        const __bf16* p = mf + (size_t)ks * 2048;
#pragma unroll
        for (int fo = 0; fo < 4; ++fo)
            dst[fo] = *reinterpret_cast<const bf16x8*>(p + fo * 512);
    };
    auto COMPUTE = [&](const bf16x8* a, const float* buf) {
        float v[8];
#pragma unroll
        for (int j = 0; j < 8; ++j) v[j] = buf[rd_off + j * 64];
        bf16x8 bx;
#pragma unroll
        for (int j = 0; j < 8; ++j) bx[j] = (__bf16)v[j];
#pragma unroll
        for (int fo = 0; fo < 4; ++fo)
            acc[fo] = __builtin_amdgcn_mfma_f32_16x16x32_bf16(a[fo], bx, acc[fo], 0, 0, 0);
    };

    float* const b0 = lds;
    float* const b1 = lds + 2048;
    float* const b2 = lds + 4096;
    float* const b3 = lds + 6144;
    bf16x8 ac[4], an[4];

    // ---- prologue (order defines steady-state vmcnt accounting) ----
    STAGE(0, b0);       // S(0)
    STAGE(1, b1);       // S(1)
    PREFA(ac, 0);       // A(0)
    STAGE(2, b2);       // S(2)
    PREFA(an, 1);       // A(1)

    // ---- main loop: iters 0..39 ----
    // iter i: wait{A(i),S(i)} = vmcnt(6); barrier; STAGE(i+3); COMPUTE(i); PREFA(i+2)
    for (int i = 0; i < 40; i += 4) {
        WAITV(6); BARR; STAGE(i + 3, b3); COMPUTE(ac, b0); PREFA(ac, i + 2);
        WAITV(6); BARR; STAGE(i + 4, b0); COMPUTE(an, b1); PREFA(an, i + 3);
        WAITV(6); BARR; STAGE(i + 5, b1); COMPUTE(ac, b2); PREFA(ac, i + 4);
        WAITV(6); BARR; STAGE(i + 6, b2); COMPUTE(an, b3); PREFA(an, i + 5);
    }

    // ---- tail: iters 40..43 ----
    WAITV(6); BARR; STAGE(43, b3); COMPUTE(ac, b0); PREFA(ac, 42);  // iter 40
    WAITV(6); BARR; COMPUTE(an, b1); PREFA(an, 43);                 // iter 41
    WAITV(4); BARR; COMPUTE(ac, b2);                                // iter 42
    WAITV(0); BARR; COMPUTE(an, b3);                                // iter 43

    // ---- store: D row o = fo*16 + kg*4 + r, col t = tt*64 + wave*16 + tcol
    float* yp = y + (size_t)b * (O_ * T_) + tt * 64 + wave * 16 + tcol;
#pragma unroll
    for (int fo = 0; fo < 4; ++fo) {
#pragma unroll
        for (int r = 0; r < 4; ++r) {
            int o = fo * 16 + kg * 4 + r;
            yp[(size_t)o * T_] = acc[fo][r] + constv[o];
        }
    }
}

// ---------------------------------------------------------------------------
extern "C" void kernel_launch(void* const* d_in, const int* in_sizes, int n_in,
                              void* d_out, int out_size, void* d_ws, size_t ws_size,
                              hipStream_t stream)
{
    (void)in_sizes; (void)n_in; (void)out_size; (void)ws_size;
    const float* x     = (const float*)d_in[0];
    const float* adjp  = (const float*)d_in[1];
    const float* chebw = (const float*)d_in[2];
    const float* chebb = (const float*)d_in[3];
    const float* aggw  = (const float*)d_in[4];
    const float* aggb  = (const float*)d_in[5];
    float* y = (float*)d_out;

    char* ws = (char*)d_ws;
    float*  Cbuf   = (float*)(ws);                    //   968 floats
    float*  constv = (float*)(ws + 4096);             //    64 floats
    float*  F      = (float*)(ws + 8192);             // 180224 floats (720896 B)
    __bf16* Mfrag  = (__bf16*)(ws + 8192 + 720896);   //  90112 bf16  (180224 B)

    hipLaunchKernelGGL(prep1, dim3(1),    dim3(512), 0, stream, adjp, aggw, chebb, aggb, Cbuf, constv);
    hipLaunchKernelGGL(prep2, dim3(128),  dim3(256), 0, stream, aggw, Cbuf, F);
    hipLaunchKernelGGL(prep3, dim3(176),  dim3(256), 0, stream, chebw, aggw, F, Mfrag);
    hipLaunchKernelGGL(gemm_main, dim3(1024), dim3(256), 0, stream, x, Mfrag, constv, y);
}

// Round 4
// 98.692 us; speedup vs baseline: 1.5103x; 1.5103x over previous
//
#include <hip/hip_runtime.h>
#include <hip/hip_bf16.h>

// Problem constants
#define B_    64
#define C_    64
#define N_    22
#define T_    1024
#define O_    64
#define KTOT  1408      // C_*N_
#define KSTEPS 44       // KTOT/32

typedef __bf16 bf16x8 __attribute__((ext_vector_type(8)));
typedef float  f32x4  __attribute__((ext_vector_type(4)));

typedef __attribute__((address_space(1))) float f32_g;
typedef __attribute__((address_space(3))) float f32_l;

// ---------------------------------------------------------------------------
// prep_all: one block per output channel o. Redundantly computes the 22x22
// graph operators (cheap), then F1/F2 for this o, const[o] (parallel
// reduction), and this o's slice of Mfrag in A-fragment-major bf16 layout:
//   Mfrag[((ks*4+fo)*64 + l)*8 + j] = M[o = fo*16 + (l&15),
//                                       k = ks*32 + (l>>4)*8 + j]
// ---------------------------------------------------------------------------
__global__ __launch_bounds__(256) void prep_all(
    const float* __restrict__ adjp,
    const float* __restrict__ chebw,   // [3][64][64]
    const float* __restrict__ chebb,   // [64]
    const float* __restrict__ aggw,    // [64][64][22]
    const float* __restrict__ aggb,    // [64]
    __bf16* __restrict__ Mfrag,        // [176*512]
    float* __restrict__ constv)        // [64]
{
    const int o   = blockIdx.x;
    const int tid = threadIdx.x;
    __shared__ float sm[484];     // s = -D^-1/2 A D^-1/2   (C1)
    __shared__ float c2[484];     // adj (temp), then C2 = 2 s^2 - I
    __shared__ float dis[22];
    __shared__ float aggs[KTOT];  // aggw[o,:,:]
    __shared__ float F1[KTOT];
    __shared__ float F2[KTOT];
    __shared__ float red[256];

    for (int e = tid; e < 484; e += 256) {
        int i = e / 22, j = e - i * 22;
        float a = 0.5f * (1.f / (1.f + expf(-adjp[i * 22 + j])) +
                          1.f / (1.f + expf(-adjp[j * 22 + i])));
        c2[e] = (i == j) ? 0.f : a;
    }
    for (int e = tid; e < KTOT; e += 256) aggs[e] = aggw[o * KTOT + e];
    __syncthreads();
    if (tid < 22) {
        float d = 0.f;
        for (int n = 0; n < 22; ++n) d += c2[tid * 22 + n];
        dis[tid] = rsqrtf(d);
    }
    __syncthreads();
    for (int e = tid; e < 484; e += 256) {
        int i = e / 22, j = e - i * 22;
        sm[e] = -dis[i] * c2[e] * dis[j];
    }
    __syncthreads();
    for (int e = tid; e < 484; e += 256) {
        int i = e / 22, j = e - i * 22;
        float acc = 0.f;
        for (int n = 0; n < 22; ++n) acc += sm[i * 22 + n] * sm[n * 22 + j];
        c2[e] = 2.f * acc - (i == j ? 1.f : 0.f);
    }
    __syncthreads();
    // F_q[cp][v] = sum_n aggs[cp*22+n] * Cq[n*22+v]
    for (int e = tid; e < KTOT; e += 256) {
        int cp = e / 22, v = e - cp * 22;
        float a1 = 0.f, a2 = 0.f;
        for (int n = 0; n < 22; ++n) {
            float w = aggs[cp * 22 + n];
            a1 += w * sm[n * 22 + v];
            a2 += w * c2[n * 22 + v];
        }
        F1[e] = a1;
        F2[e] = a2;
    }
    // const[o] partial sums (uses aggs + chebb only)
    float p = 0.f;
    for (int e = tid; e < KTOT; e += 256) p += aggs[e] * chebb[e / 22];
    red[tid] = p;
    __syncthreads();   // covers F1/F2 writes and red
#pragma unroll
    for (int st = 128; st > 0; st >>= 1) {
        if (tid < st) red[tid] += red[tid + st];
        __syncthreads();
    }
    if (tid == 0) constv[o] = red[0] + aggb[o];

    // M[o,k] = sum_cp W0[c,cp]*aggs[cp,v] + W1[c,cp]*F1[cp,v] + W2[c,cp]*F2[cp,v]
    const int fo = o >> 4, l15 = o & 15;
    for (int k = tid; k < KTOT; k += 256) {
        int c = k / 22, v = k - c * 22;
        const float* w0 = chebw + c * 64;
        float a0 = 0.f, a1 = 0.f, a2 = 0.f;
        for (int cp = 0; cp < 64; ++cp) {
            int idx = cp * 22 + v;
            a0 += w0[cp] * aggs[idx];
            a1 += w0[4096 + cp] * F1[idx];
            a2 += w0[8192 + cp] * F2[idx];
        }
        int ks = k >> 5, r = k & 31, lhi = r >> 3, j = r & 7;
        Mfrag[(((ks * 4 + fo) * 64) + lhi * 16 + l15) * 8 + j] = (__bf16)(a0 + a1 + a2);
    }
}

// ---------------------------------------------------------------------------
// main GEMM: per block (b, t-quarter of 256): Y[64, tq*256:+256] = M @ X_b
// 512 threads (8 waves, wave owns t-sub of 32 = two 16-col MFMA tiles).
// x staged 32 rows x 1 KB contiguous per row (4x DRAM granularity vs t=64).
// 3 x 32 KB LDS buffers, stage distance 2, steady vmcnt(4) (never 0 in loop).
// Source-side chunk-XOR swizzle -> ds_read at free 2-way bank aliasing.
// ---------------------------------------------------------------------------
#define WAITV(N) asm volatile("s_waitcnt vmcnt(" #N ")" ::: "memory")
#define BARR do { __builtin_amdgcn_s_barrier(); __builtin_amdgcn_sched_barrier(0); } while (0)

__global__ __launch_bounds__(512, 2) void gemm_main(
    const float* __restrict__ x,
    const __bf16* __restrict__ Mfrag,
    const float* __restrict__ constv,
    float* __restrict__ y)
{
    __shared__ float lds[3 * 8192];   // 3 x [32 k][256 t] fp32 = 96 KB

    // XCD swizzle: 256 blocks -> 32 per XCD (bijective, 256 % 8 == 0)
    const int bid  = ((blockIdx.x & 7) << 5) | (blockIdx.x >> 3);
    const int b    = bid >> 2;
    const int tq   = bid & 3;
    const int wave = threadIdx.x >> 6;
    const int lane = threadIdx.x & 63;
    const int tcol = lane & 15;
    const int kg   = lane >> 4;

    // ---- staging: wave stages rows r = wave*4+q (one gload_lds per row).
    // LDS chunk c (64 B) of row r holds global t-chunk c ^ ((r>>3)&1);
    // swizzle applied on per-lane SOURCE address (LDS dest is lane-linear).
    const size_t xbase = (size_t)b * (KTOT * T_) + tq * 256;

    // ---- fragment read addressing (inverse swizzle) ----
    // lane reads x[k=kg*8+j][t=wave*32+m*16+tcol]: chunk (wave*2+m)^(kg&1)
    const int rd0 = kg * 8 * 256 + (((wave * 2 + 0) ^ (kg & 1)) << 4) + tcol;
    const int rd1 = kg * 8 * 256 + (((wave * 2 + 1) ^ (kg & 1)) << 4) + tcol;

    const __bf16* mf = Mfrag + (size_t)lane * 8;

    f32x4 acc[2][4];
#pragma unroll
    for (int m = 0; m < 2; ++m)
#pragma unroll
        for (int fo = 0; fo < 4; ++fo) acc[m][fo] = (f32x4){0.f, 0.f, 0.f, 0.f};

    auto STAGE = [&](int ks, float* buf) {
#pragma unroll
        for (int q = 0; q < 4; ++q) {
            const int r = wave * 4 + q;
            const int g = (((lane >> 2) ^ ((r >> 3) & 1)) << 4) + (lane & 3) * 4;
            const float* src = x + xbase + (size_t)(ks * 32 + r) * T_ + g;
            __builtin_amdgcn_global_load_lds((const f32_g*)src, (f32_l*)(buf + r * 256), 16, 0, 0);
        }
    };
    auto PREFA = [&](bf16x8* dst, int ks) {
        const __bf16* p = mf + (size_t)ks * 2048;
#pragma unroll
        for (int fo = 0; fo < 4; ++fo)
            dst[fo] = *reinterpret_cast<const bf16x8*>(p + fo * 512);
    };
    auto COMPUTE = [&](const bf16x8* a, const float* buf) {
#pragma unroll
        for (int m = 0; m < 2; ++m) {
            const int rb = (m == 0) ? rd0 : rd1;
            float v[8];
#pragma unroll
            for (int j = 0; j < 8; ++j) v[j] = buf[rb + j * 256];
            bf16x8 bx;
#pragma unroll
            for (int j = 0; j < 8; ++j) bx[j] = (__bf16)v[j];
#pragma unroll
            for (int fo = 0; fo < 4; ++fo)
                acc[m][fo] = __builtin_amdgcn_mfma_f32_16x16x32_bf16(a[fo], bx, acc[m][fo], 0, 0, 0);
        }
    };

    float* const b0 = lds;
    float* const b1 = lds + 8192;
    float* const b2 = lds + 16384;
    bf16x8 ac[4], an[4];

    // ---- prologue: chronological VMEM order [S0, A0, S1] ----
    STAGE(0, b0);
    PREFA(ac, 0);
    STAGE(1, b1);

    // ---- main loop: iters 0..41 (42 = 6*7; buffer period 3, frag period 2)
    // iter i: WAITV(4) drains {S_i, A_i}, keeps S_{i+1}; issue A(i+1), S(i+2)
    for (int i = 0; i < 42; i += 6) {
        WAITV(4); BARR; PREFA(an, i + 1); STAGE(i + 2, b2); COMPUTE(ac, b0);
        WAITV(4); BARR; PREFA(ac, i + 2); STAGE(i + 3, b0); COMPUTE(an, b1);
        WAITV(4); BARR; PREFA(an, i + 3); STAGE(i + 4, b1); COMPUTE(ac, b2);
        WAITV(4); BARR; PREFA(ac, i + 4); STAGE(i + 5, b2); COMPUTE(an, b0);
        WAITV(4); BARR; PREFA(an, i + 5); STAGE(i + 6, b0); COMPUTE(ac, b1);
        WAITV(4); BARR; PREFA(ac, i + 6); STAGE(i + 7, b1); COMPUTE(an, b2);
    }

    // ---- tail: iters 42 (buf b0, frag ac), 43 (buf b1, frag an) ----
    WAITV(4); BARR; PREFA(an, 43); COMPUTE(ac, b0);
    WAITV(0); BARR; COMPUTE(an, b1);

    // ---- store: o = fo*16 + kg*4 + rr, t = tq*256 + wave*32 + m*16 + tcol
    float* yp = y + (size_t)b * (O_ * T_) + tq * 256 + wave * 32 + tcol;
#pragma unroll
    for (int m = 0; m < 2; ++m)
#pragma unroll
        for (int fo = 0; fo < 4; ++fo)
#pragma unroll
            for (int rr = 0; rr < 4; ++rr) {
                int o = fo * 16 + kg * 4 + rr;
                yp[(size_t)o * T_ + m * 16] = acc[m][fo][rr] + constv[o];
            }
}

// ---------------------------------------------------------------------------
extern "C" void kernel_launch(void* const* d_in, const int* in_sizes, int n_in,
                              void* d_out, int out_size, void* d_ws, size_t ws_size,
                              hipStream_t stream)
{
    (void)in_sizes; (void)n_in; (void)out_size; (void)ws_size;
    const float* x     = (const float*)d_in[0];
    const float* adjp  = (const float*)d_in[1];
    const float* chebw = (const float*)d_in[2];
    const float* chebb = (const float*)d_in[3];
    const float* aggw  = (const float*)d_in[4];
    const float* aggb  = (const float*)d_in[5];
    float* y = (float*)d_out;

    char* ws = (char*)d_ws;
    float*  constv = (float*)(ws);                 // 64 floats
    __bf16* Mfrag  = (__bf16*)(ws + 4096);         // 90112 bf16 (180224 B)

    hipLaunchKernelGGL(prep_all, dim3(64), dim3(256), 0, stream,
                       adjp, chebw, chebb, aggw, aggb, Mfrag, constv);
    hipLaunchKernelGGL(gemm_main, dim3(256), dim3(512), 0, stream,
                       x, Mfrag, constv, y);
}